// Round 16
// baseline (105.395 us; speedup 1.0000x reference)
//
#include <hip/hip_runtime.h>
#include <math.h>

// ChamferDistance: B=4, N=M=8192, 3-D fp32 points.
// out[0] = mean_i sqrt(min_j d2)*w  +  mean_j sqrt(min_i d2)
//
// MFMA formulation (R6+): d2 = qsq + (rsq - 2 q.r) as a K=5 dot on
// v_mfma_f32_32x32x16_f16 (32 refs x 32 queries = 1024 pairs/inst):
//   A (refs)    = (-2rx,-2ry,-2rz, rsq_hi, rsq_lo, ...) f16
//   B (queries) = (  qx,  qy,  qz,   1,      1,    0,0,0) f16, lanes 0-31;
//   lanes 32-63 of B are ZERO -> k=8..15 contributes nothing, so A's upper
//   lane-half may hold ANY finite data (we let it mirror the lower half —
//   no zero-slot, no divergent LDS addressing).
// D: col=lane&31=query; 16 regs x lane-half = 32 refs -> per-lane min3
// fold + one shfl_xor(32). absmax 0.0 verified across R6-R15.
//
// R16: MAXIMAL FUSION. R9-R15 falsified every scheduling theory; the
// remaining controllable cost is nn (~16us) + reduce (~3) + gaps. Here
// each block resolves its 128 queries against ALL 8192 refs via 4 staged
// LDS chunks (global loads for chunk c+1 issued before chunk c's K-loop),
// then computes sqrt/weight/sum inline -> ONE float per block. 512 blocks
// = 2/CU, 1 wave/SIMD; steady state 2 MFMAs (64 matrix-cyc) cover
// 1 ds_read + 16 min3 (~46 issue-cyc) -> matrix-bound: 512 MFMA x 32.3cyc
// = 6.9us + staging. Depth-2 LDS ring prefetch (full unroll) covers the
// 120cyc DS latency. Two dispatches total; no memset, no atomics.

#define EPS 1e-8f

typedef _Float16 f16x8 __attribute__((ext_vector_type(8)));
typedef float    f32x16 __attribute__((ext_vector_type(16)));

constexpr int B_    = 4;
constexpr int N_    = 8192;           // points per batch (N == M)
constexpr int TPB   = 128;            // 2 waves
constexpr int QPW   = 64;             // queries per wave (2 tiles of 32)
constexpr int QPB   = 2 * QPW;        // 128 queries per block
constexpr int CHUNK = 2048;           // refs per LDS stage (32 KB)
constexpr int NCH   = N_ / CHUNK;     // 4 stages
constexpr int NF    = CHUNK / 32;     // 64 A-fragments per stage
constexpr int RPT   = CHUNK / TPB;    // 16 refs staged per thread
constexpr int QBLK  = N_ / QPB;       // 64 query-blocks per (dir,b)
constexpr int NBLK  = QBLK * 2 * B_;  // 512 blocks

#define FOLD(d, ma, mb)                                         \
    _Pragma("unroll")                                           \
    for (int r = 0; r < 8; r += 2)                              \
        ma = fminf(fminf(d[r], d[r + 1]), ma);                  \
    _Pragma("unroll")                                           \
    for (int r = 8; r < 16; r += 2)                             \
        mb = fminf(fminf(d[r], d[r + 1]), mb);

// grid: (QBLK=64, 2*B=8) = 512 blocks, 2 per CU.
__global__ __launch_bounds__(TPB, 1)
void nn_fused_kernel(const float* __restrict__ src, const float* __restrict__ tgt,
                     const float* __restrict__ w, float* __restrict__ bpart)
{
    __shared__ f16x8 sref[CHUNK];        // 32 KB
    __shared__ float ss[TPB / 64];

    const int zb  = blockIdx.y;
    const int dir = zb >> 2;             // 0: src queries tgt, 1: tgt queries src
    const int b   = zb & 3;
    const float* Rraw = (dir ? src : tgt) + (size_t)b * N_ * 3;
    const float* Qraw = (dir ? tgt : src) + (size_t)b * N_ * 3;

    const int tid  = threadIdx.x;
    const int lane = tid & 63;
    const int wv   = tid >> 6;
    const int l31  = lane & 31;
    const int half = lane >> 5;
    const int qb   = blockIdx.x * QPB + wv * QPW;

    const _Float16 h0 = (_Float16)0.f;
    const _Float16 h1 = (_Float16)1.f;

    // queries: all lanes load (qs needed everywhere); B upper half stays 0
    f16x8 B0 = {h0, h0, h0, h0, h0, h0, h0, h0};
    f16x8 B1 = B0;
    float qs0, qs1;
    {
        const float* q0 = Qraw + (size_t)(qb + l31) * 3;
        const float* q1 = Qraw + (size_t)(qb + 32 + l31) * 3;
        _Float16 ax = (_Float16)q0[0], ay = (_Float16)q0[1], az = (_Float16)q0[2];
        _Float16 bx = (_Float16)q1[0], by = (_Float16)q1[1], bz = (_Float16)q1[2];
        float fax = (float)ax, fay = (float)ay, faz = (float)az;
        float fbx = (float)bx, fby = (float)by, fbz = (float)bz;
        qs0 = fax * fax + fay * fay + faz * faz;
        qs1 = fbx * fbx + fby * fby + fbz * fbz;
        if (half == 0) {
            B0 = f16x8{ax, ay, az, h1, h1, h0, h0, h0};
            B1 = f16x8{bx, by, bz, h1, h1, h0, h0, h0};
        }
    }

    // stage-ahead registers: chunk 0 loads issued immediately
    float rx[RPT], ry[RPT], rz[RPT];
#pragma unroll
    for (int i = 0; i < RPT; ++i) {
        const float* rp = Rraw + (size_t)(i * TPB + tid) * 3;
        rx[i] = rp[0]; ry[i] = rp[1]; rz[i] = rp[2];
    }

    const f32x16 zc = {};
    float mn0a = 3.0e38f, mn0b = 3.0e38f, mn1a = 3.0e38f, mn1b = 3.0e38f;

    for (int c = 0; c < NCH; ++c) {
        __syncthreads();                 // prior K-loop done with LDS
        // quantize staged regs -> LDS: (-2x,-2y,-2z, rsq_hi, rsq_lo, 0,0,0)
#pragma unroll
        for (int i = 0; i < RPT; ++i) {
            _Float16 hx = (_Float16)rx[i], hy = (_Float16)ry[i], hz = (_Float16)rz[i];
            float fx = (float)hx, fy = (float)hy, fz = (float)hz;
            float rsq = fx * fx + fy * fy + fz * fz;
            _Float16 rh = (_Float16)rsq;
            _Float16 rl = (_Float16)(rsq - (float)rh);
            sref[i * TPB + tid] = f16x8{(_Float16)(-2.f * fx), (_Float16)(-2.f * fy),
                                        (_Float16)(-2.f * fz), rh, rl, h0, h0, h0};
        }
        __syncthreads();
        // kick off next chunk's global loads; consumed at next quantize
        if (c + 1 < NCH) {
            const float* Rc = Rraw + (size_t)(c + 1) * CHUNK * 3;
#pragma unroll
            for (int i = 0; i < RPT; ++i) {
                const float* rp = Rc + (size_t)(i * TPB + tid) * 3;
                rx[i] = rp[0]; ry[i] = rp[1]; rz[i] = rp[2];
            }
        }

        // K-loop: 64 frags, depth-2 LDS ring prefetch, depth-1 D fold
        // pipeline; ALL lanes read slot f*32+l31 (upper half mirrors lower).
        f16x8 A0 = sref[l31];
        f16x8 Ax = sref[32 + l31];
        f16x8 Ay = sref[64 + l31];
        f32x16 dP0 = __builtin_amdgcn_mfma_f32_32x32x16_f16(A0, B0, zc, 0, 0, 0);
        f32x16 dP1 = __builtin_amdgcn_mfma_f32_32x32x16_f16(A0, B1, zc, 0, 0, 0);
#pragma unroll
        for (int f = 1; f < NF; ++f) {
            f32x16 dC0 = __builtin_amdgcn_mfma_f32_32x32x16_f16(Ax, B0, zc, 0, 0, 0);
            f32x16 dC1 = __builtin_amdgcn_mfma_f32_32x32x16_f16(Ax, B1, zc, 0, 0, 0);
            f16x8 An = (f + 2 < NF) ? sref[(f + 2) * 32 + l31] : Ay;
            FOLD(dP0, mn0a, mn0b)
            FOLD(dP1, mn1a, mn1b)
            dP0 = dC0; dP1 = dC1;        // renamed away by full unroll
            Ax = Ay; Ay = An;
        }
        FOLD(dP0, mn0a, mn0b)
        FOLD(dP1, mn1a, mn1b)
    }

    // epilogue: NN fully resolved in-block. Halves hold duplicate values
    // after the xor-32 merge -> sum all 64 lanes, correct by 0.5 in reduce2.
    float mn0 = fminf(mn0a, mn0b);
    float mn1 = fminf(mn1a, mn1b);
    mn0 = fminf(mn0, __shfl_xor(mn0, 32));
    mn1 = fminf(mn1, __shfl_xor(mn1, 32));
    float d0 = sqrtf(fmaxf(mn0 + qs0, 0.f) + EPS);
    float d1 = sqrtf(fmaxf(mn1 + qs1, 0.f) + EPS);
    float sl;
    if (dir == 0) {
        const float* wb = w + (size_t)b * N_;
        sl = d0 * wb[qb + l31] + d1 * wb[qb + 32 + l31];
    } else {
        sl = d0 + d1;
    }
#pragma unroll
    for (int off = 32; off > 0; off >>= 1) sl += __shfl_down(sl, off);
    if (lane == 0) ss[wv] = sl;
    __syncthreads();
    if (tid == 0) bpart[blockIdx.y * QBLK + blockIdx.x] = ss[0] + ss[1];
}

// final: one block sums the 512 block-partials (each 2x true due to
// lane-half duplication) -> out[0] = total * 0.5 / (B*N).
__global__ __launch_bounds__(NBLK)
void reduce2_kernel(const float* __restrict__ bpart, float* __restrict__ out)
{
    __shared__ float ss[NBLK / 64];
    float v = bpart[threadIdx.x];
#pragma unroll
    for (int off = 32; off > 0; off >>= 1) v += __shfl_down(v, off);
    int lane = threadIdx.x & 63, wid = threadIdx.x >> 6;
    if (lane == 0) ss[wid] = v;
    __syncthreads();
    if (threadIdx.x == 0) {
        float s = 0.f;
#pragma unroll
        for (int i = 0; i < NBLK / 64; ++i) s += ss[i];
        out[0] = s * 0.5f / (float)(B_ * N_);
    }
}

extern "C" void kernel_launch(void* const* d_in, const int* in_sizes, int n_in,
                              void* d_out, int out_size, void* d_ws, size_t ws_size,
                              hipStream_t stream)
{
    const float* src = (const float*)d_in[0];   // (B, N, 3)
    const float* tgt = (const float*)d_in[1];   // (B, M, 3)
    const float* w   = (const float*)d_in[2];   // (B, N)
    float* out = (float*)d_out;

    float* bpart = (float*)d_ws;   // 512 floats, all written

    dim3 grid(QBLK, 2 * B_);       // 64 x 8 = 512 blocks
    nn_fused_kernel<<<grid, TPB, 0, stream>>>(src, tgt, w, bpart);
    reduce2_kernel<<<1, NBLK, 0, stream>>>(bpart, out);
}

// Round 18
// 76.603 us; speedup vs baseline: 1.3759x; 1.3759x over previous
//
#include <hip/hip_runtime.h>
#include <math.h>

// ChamferDistance: B=4, N=M=8192, 3-D fp32 points.
// out[0] = mean_i sqrt(min_j d2)*w  +  mean_j sqrt(min_i d2)
//
// MFMA formulation (R6+): d2 = qsq + (rsq - 2 q.r) as a K=5 dot on
// v_mfma_f32_32x32x16_f16 (32 refs x 32 queries = 1024 pairs/inst):
//   A (refs)    = (-2rx,-2ry,-2rz, rsq_hi, rsq_lo, 0,0,0) f16, lanes 0-31
//   B (queries) = (  qx,  qy,  qz,   1,      1,    0,0,0) f16, lanes 0-31
// lanes 32-63 (k=8..15) zero. D: col=lane&31=query; 16 regs x lane-half =
// 32 refs -> per-lane min3 fold + one shfl_xor(32). absmax 0.0 (R6-R16).
//
// R18 = R17 + sched_barrier fences. R16's counters showed ~26.7K VALU
// inst/wave vs ~5.5K modeled: builtin MFMA defs land in AGPRs and each
// fold pays 16 v_accvgpr_read per MFMA (24 inst vs 8) — present in all
// R6-R15 variants, explaining their invariance to scheduling changes.
// R17 defined D directly in VGPRs via asm but FAILED (absmax 6.4e-2):
// the machine scheduler hoisted v_min3 folds against the asm def,
// violating the MFMA->VALU read hazard (~17 wait states; compiler only
// pads builtins with s_nop). Fix: __builtin_amdgcn_sched_barrier(0)
// between every MFMA-issue group and fold group pins the hand schedule:
// each D is read >=32 issue slots after its def — past the hazard window
// — while the depth-1 ping-pong overlap is preserved.

#define EPS 1e-8f

typedef _Float16 f16x8 __attribute__((ext_vector_type(8)));
typedef float    f32x16 __attribute__((ext_vector_type(16)));

static __device__ __forceinline__ f32x16 mfma_v(f16x8 a, f16x8 b) {
    f32x16 d;
    asm("v_mfma_f32_32x32x16_f16 %0, %1, %2, 0"
        : "=&v"(d) : "v"(a), "v"(b));
    return d;
}
#define SB() __builtin_amdgcn_sched_barrier(0)

constexpr int B_    = 4;
constexpr int N_    = 8192;          // points per batch (N == M)
constexpr int TPB   = 256;           // 4 waves
constexpr int QPW   = 64;            // queries per wave (2 tiles of 32)
constexpr int QPB   = 4 * QPW;       // 256 queries per block
constexpr int RCH   = 8;             // ref chunks (grid.y)
constexpr int CHUNK = N_ / RCH;      // 1024 refs staged per block (16 KB)
constexpr int RB    = 64;            // reduce blocks

#define FOLD(d, ma, mb)                                         \
    _Pragma("unroll")                                           \
    for (int r = 0; r < 8; r += 2)                              \
        ma = fminf(fminf(d[r], d[r + 1]), ma);                  \
    _Pragma("unroll")                                           \
    for (int r = 8; r < 16; r += 2)                             \
        mb = fminf(fminf(d[r], d[r + 1]), mb);

// grid: (N/QPB=32, RCH=8, 2*B=8) = 2048 blocks.
// part layout: part[(zb*RCH + c)*N + q]  (zb = dir*4+b), 2 MB total.
__global__ __launch_bounds__(TPB, 4)
void nn_mfma_kernel(const float* __restrict__ src, const float* __restrict__ tgt,
                    float* __restrict__ part, float* __restrict__ out)
{
    __shared__ f16x8 sref[CHUNK + 64];   // +64: zero slots / tail-read pad

    if (blockIdx.x == 0 && blockIdx.y == 0 && blockIdx.z == 0 && threadIdx.x == 0)
        out[0] = 0.f;                    // reduce (next dispatch) atomicAdds

    const int zb  = blockIdx.z;
    const int dir = zb >> 2;            // 0: src queries tgt, 1: tgt queries src
    const int b   = zb & 3;
    const float* Rraw = (dir ? src : tgt) + ((size_t)b * N_ + (size_t)blockIdx.y * CHUNK) * 3;
    const float* Qraw = (dir ? tgt : src) + (size_t)b * N_ * 3;
    float* opart = part + ((size_t)zb * RCH + blockIdx.y) * N_;

    const int tid = threadIdx.x;
    const _Float16 h0 = (_Float16)0.f;
    const _Float16 h1 = (_Float16)1.f;

    // stage + quantize refs inline: (-2x,-2y,-2z, rsq_hi, rsq_lo, 0,0,0)
    for (int k = tid; k < CHUNK; k += TPB) {
        const float* rp = Rraw + (size_t)k * 3;
        _Float16 hx = (_Float16)rp[0], hy = (_Float16)rp[1], hz = (_Float16)rp[2];
        float fx = (float)hx, fy = (float)hy, fz = (float)hz;
        float rsq = fx * fx + fy * fy + fz * fz;
        _Float16 rh = (_Float16)rsq;
        _Float16 rl = (_Float16)(rsq - (float)rh);
        f16x8 a = {(_Float16)(-2.f * fx), (_Float16)(-2.f * fy),
                   (_Float16)(-2.f * fz), rh, rl, h0, h0, h0};
        sref[k] = a;
    }
    if (tid < 64) {
        f16x8 z = {h0, h0, h0, h0, h0, h0, h0, h0};
        sref[CHUNK + tid] = z;
    }

    const int lane = tid & 63;
    const int wv   = tid >> 6;
    const int l31  = lane & 31;
    const int half = lane >> 5;          // 0: carries data (k=0..7), 1: zeros
    const int qb   = blockIdx.x * QPB + wv * QPW;

    // B fragments quantized inline; lanes 32-63 stay zero (k=8..15)
    f16x8 B0 = {h0, h0, h0, h0, h0, h0, h0, h0};
    f16x8 B1 = B0;
    float qs0 = 0.f, qs1 = 0.f;
    if (half == 0) {
        const float* q0 = Qraw + (size_t)(qb + l31) * 3;
        const float* q1 = Qraw + (size_t)(qb + 32 + l31) * 3;
        _Float16 ax = (_Float16)q0[0], ay = (_Float16)q0[1], az = (_Float16)q0[2];
        _Float16 bx = (_Float16)q1[0], by = (_Float16)q1[1], bz = (_Float16)q1[2];
        float fax = (float)ax, fay = (float)ay, faz = (float)az;
        float fbx = (float)bx, fby = (float)by, fbz = (float)bz;
        B0 = f16x8{ax, ay, az, h1, h1, h0, h0, h0};
        B1 = f16x8{bx, by, bz, h1, h1, h0, h0, h0};
        qs0 = fax * fax + fay * fay + faz * faz;
        qs1 = fbx * fbx + fby * fby + fbz * fbz;
    }
    __syncthreads();

    // Depth-1 pipelined K-loop, hand-scheduled and pinned with SB():
    // {MFMA pair} | {ds_read + folds of previous D} | {MFMA pair} | ...
    // Every D read happens >=32 issue slots after its defining MFMA.
    int idx = (half == 0) ? l31 : CHUNK;
    const int step = (half == 0) ? 32 : 0;
    float mn0a = 3.0e38f, mn0b = 3.0e38f, mn1a = 3.0e38f, mn1b = 3.0e38f;

    f16x8 a = sref[idx];
    idx += step;
    f32x16 dA0 = mfma_v(a, B0);
    f32x16 dA1 = mfma_v(a, B1);
    SB();
    a = sref[idx];
    idx += step;
    for (int s = 0; s < 15; ++s) {
        f32x16 dB0 = mfma_v(a, B0);
        f32x16 dB1 = mfma_v(a, B1);
        SB();
        a = sref[idx];
        idx += step;
        FOLD(dA0, mn0a, mn0b)
        FOLD(dA1, mn1a, mn1b)
        SB();
        dA0 = mfma_v(a, B0);
        dA1 = mfma_v(a, B1);
        SB();
        a = sref[idx];
        idx += step;
        FOLD(dB0, mn0a, mn0b)
        FOLD(dB1, mn1a, mn1b)
        SB();
    }
    {
        f32x16 dB0 = mfma_v(a, B0);
        f32x16 dB1 = mfma_v(a, B1);
        SB();
        FOLD(dA0, mn0a, mn0b)
        FOLD(dA1, mn1a, mn1b)
        SB();
        FOLD(dB0, mn0a, mn0b)
        FOLD(dB1, mn1a, mn1b)
    }

    float mn0 = fminf(mn0a, mn0b);
    float mn1 = fminf(mn1a, mn1b);
    // rows split across lane halves: one xor-32 merge covers all 32 refs/tile
    mn0 = fminf(mn0, __shfl_xor(mn0, 32));
    mn1 = fminf(mn1, __shfl_xor(mn1, 32));
    if (half == 0) {
        opart[qb + l31]      = fmaxf(mn0 + qs0, 0.f);   // plain store, no init
        opart[qb + 32 + l31] = fmaxf(mn1 + qs1, 0.f);
    }
}

// reduce: per query min over RCH partials -> sqrt -> weight -> sum ->
// atomicAdd into out[0] (zeroed by nn). 2 MB of partials, L2-resident.
__global__ __launch_bounds__(TPB)
void reduce_kernel(const float* __restrict__ part,
                   const float* __restrict__ w,
                   float* __restrict__ out)
{
    const int Q = 2 * B_ * N_;               // 65536 queries
    const float invBN = 1.0f / (float)(B_ * N_);

    float sum = 0.0f;
    for (int t = blockIdx.x * TPB + threadIdx.x; t < Q; t += RB * TPB) {
        const int zb = t >> 13;              // t / N_
        const int qn = t & (N_ - 1);
        const float* p = part + ((size_t)zb * RCH) * N_ + qn;
        float m = p[0];
#pragma unroll
        for (int c = 1; c < RCH; ++c) m = fminf(m, p[(size_t)c * N_]);
        float d = sqrtf(m + EPS);
        sum += (zb < 4) ? d * w[(size_t)zb * N_ + qn] : d;
    }
    sum *= invBN;

    __shared__ float ss[TPB / 64];
    int lane = threadIdx.x & 63;
    int wid  = threadIdx.x >> 6;
#pragma unroll
    for (int off = 32; off > 0; off >>= 1) sum += __shfl_down(sum, off);
    if (lane == 0) ss[wid] = sum;
    __syncthreads();
    if (threadIdx.x == 0) {
        float s = 0.0f;
#pragma unroll
        for (int i = 0; i < TPB / 64; ++i) s += ss[i];
        atomicAdd(out, s);
    }
}

extern "C" void kernel_launch(void* const* d_in, const int* in_sizes, int n_in,
                              void* d_out, int out_size, void* d_ws, size_t ws_size,
                              hipStream_t stream)
{
    const float* src = (const float*)d_in[0];   // (B, N, 3)
    const float* tgt = (const float*)d_in[1];   // (B, M, 3)
    const float* w   = (const float*)d_in[2];   // (B, N)
    float* out = (float*)d_out;

    float* part = (float*)d_ws;   // [2*B][RCH][N] = 2 MB, fully overwritten

    dim3 grid(N_ / QPB, RCH, 2 * B_);   // 32 x 8 x 8 = 2048 blocks
    nn_mfma_kernel<<<grid, TPB, 0, stream>>>(src, tgt, part, out);

    reduce_kernel<<<RB, TPB, 0, stream>>>(part, w, out);
}